// Round 1
// baseline (1408.023 us; speedup 1.0000x reference)
//
#include <hip/hip_runtime.h>
#include <hip/hip_bf16.h>

// ---------------- types ----------------
typedef __attribute__((ext_vector_type(4))) float  f32x4;
typedef __attribute__((ext_vector_type(2))) float  f32x2;
typedef __attribute__((ext_vector_type(4))) short  s16x4;
typedef __attribute__((ext_vector_type(8))) short  s16x8;
typedef __attribute__((ext_vector_type(8))) __bf16 v8bf;

__device__ __forceinline__ short f2bf(float f) {
    unsigned u = __builtin_bit_cast(unsigned, f);
    unsigned r = (u + 0x7fffu + ((u >> 16) & 1u)) >> 16;   // RNE
    return (short)r;
}
__device__ __forceinline__ float bf2f(short s) {
    unsigned u = ((unsigned)(unsigned short)s) << 16;
    return __builtin_bit_cast(float, u);
}
__device__ __forceinline__ v8bf as_bf(s16x8 x) { return __builtin_bit_cast(v8bf, x); }

// ---------------- kernel 1: level-select + RoI-align ----------------
// out: flat [Nroi][512*49] fp32, layout c*49 + oy*7 + ox (matches reshape of [N,C,7,7])
__global__ __launch_bounds__(256) void roi_pool_kernel(
    const float* __restrict__ feat2, const float* __restrict__ feat3,
    const float* __restrict__ feat4, const float* __restrict__ rois,
    const int* __restrict__ roi_idx, float* __restrict__ out) {
    const int r = blockIdx.x;
    const float y1r = rois[r*4+0], x1r = rois[r*4+1];
    const float y2r = rois[r*4+2], x2r = rois[r*4+3];
    const float rh = y2r - y1r + 1.0f, rw = x2r - x1r + 1.0f;
    float lvlf = rintf(log2f(sqrtf(rh*rw) / 224.0f) + 4.0f);
    lvlf = fminf(fmaxf(lvlf, 2.0f), 4.0f);
    const int lvl = (int)lvlf;
    const float* feat; int H; float scale;
    if (lvl == 2)      { feat = feat2; H = 200; scale = 0.25f;   }
    else if (lvl == 3) { feat = feat3; H = 100; scale = 0.125f;  }
    else               { feat = feat4; H = 50;  scale = 0.0625f; }
    const int W = H;
    const int b = roi_idx[r];

    // boxes_xyxy = rois[:, [1,0,3,2]]  -> x1=rois[1], y1=rois[0], x2=rois[3], y2=rois[2]
    const float x1 = x1r*scale, y1 = y1r*scale, x2 = x2r*scale, y2 = y2r*scale;
    const float roiw = fmaxf(x2 - x1, 1.0f), roih = fmaxf(y2 - y1, 1.0f);

    __shared__ int   sy0[14], sy1[14], sx0[14], sx1[14];
    __shared__ float sly[14], slx[14];
    const int t = threadIdx.x;
    if (t < 14) {
        float off = ((float)t + 0.5f) * (1.0f/14.0f);
        float ys = fminf(fmaxf(y1 + roih*off, 0.0f), (float)(H-1));
        float yf = floorf(ys);
        sy0[t] = (int)yf; sly[t] = ys - yf; sy1[t] = min((int)yf + 1, H-1);
    } else if (t < 28) {
        int j = t - 14;
        float off = ((float)j + 0.5f) * (1.0f/14.0f);
        float xs = fminf(fmaxf(x1 + roiw*off, 0.0f), (float)(W-1));
        float xf = floorf(xs);
        sx0[j] = (int)xf; slx[j] = xs - xf; sx1[j] = min((int)xf + 1, W-1);
    }
    __syncthreads();

    const float* fb = feat + (size_t)b * 512 * H * W;
    float* ob = out + (size_t)r * 25088;
    for (int idx = t; idx < 25088; idx += 256) {
        const int c = idx / 49, p = idx % 49;
        const int oy = p / 7, ox = p % 7;
        const float* fc = fb + (size_t)c * H * W;
        float acc = 0.0f;
        #pragma unroll
        for (int sy = 0; sy < 2; ++sy) {
            const int iy = oy*2 + sy;
            const int ya = sy0[iy], yb = sy1[iy];
            const float ly = sly[iy], wy0 = 1.0f - ly;
            const float* r0 = fc + (size_t)ya * W;
            const float* r1 = fc + (size_t)yb * W;
            #pragma unroll
            for (int sx = 0; sx < 2; ++sx) {
                const int ix = ox*2 + sx;
                const int xa = sx0[ix], xb = sx1[ix];
                const float lx = slx[ix], wx0 = 1.0f - lx;
                acc += r0[xa]*wy0*wx0 + r0[xb]*wy0*lx
                     + r1[xa]*ly*wx0  + r1[xb]*ly*lx;
            }
        }
        ob[idx] = acc * 0.25f;
    }
}

// ---------------- kernel 2: split-bf16 MFMA GEMM (fp32 in, fp32 partial out) ----------
// C_partial[ks] = A[M=512, K] * B[K, N], tile 128x128, BK=32, 512 thr (8 waves 4mx2n)
// LDS k-panel layout: elem(kg, row, sub) = (kg<<10) + row*8 + sub, XOR (kg<<4) swizzle.
#define GKS 4
__global__ __launch_bounds__(512) void gemm_split_kernel(
    const float* __restrict__ A, const float* __restrict__ B,
    float* __restrict__ P, int K, int N, int ksub) {
    __shared__ unsigned short As_hi[4096], As_lo[4096], Bs_hi[4096], Bs_lo[4096];

    const int tid = threadIdx.x;
    const int m0 = blockIdx.y * 128;
    const int n0 = blockIdx.x * 128;
    const int k0base = blockIdx.z * ksub;
    const int nsteps = ksub >> 5;

    const int w    = tid >> 6;
    const int lane = tid & 63;
    const int wm   = w >> 1;           // 0..3 -> rows wm*32
    const int wn   = w & 1;            // 0..1 -> cols wn*64
    const int lr   = lane & 15;
    const int lg   = lane >> 4;        // k-group 0..3

    f32x4 acc[2][4];
    #pragma unroll
    for (int i = 0; i < 2; ++i)
        #pragma unroll
        for (int j = 0; j < 4; ++j) acc[i][j] = f32x4{0.f, 0.f, 0.f, 0.f};

    const int a_m  = tid >> 3;   // 0..63 (and +64 second task)
    const int a_kc = tid & 7;    // 4-elem k-chunk
    const int b_np = tid & 63;   // n-pair
    const int b_kq = tid >> 6;   // 0..7 (4 k-rows each)

    for (int step = 0; step < nsteps; ++step) {
        const int k0 = k0base + (step << 5);
        // ---- stage A (two rows: a_m, a_m+64) ----
        {
            const float* ap = A + (size_t)(m0 + a_m) * K + k0 + a_kc * 4;
            f32x4 v0 = *(const f32x4*)ap;
            f32x4 v1 = *(const f32x4*)(ap + (size_t)64 * K);
            const int kg = a_kc >> 1, sub0 = (a_kc & 1) * 4;
            const int e0 = (((kg << 10) + a_m * 8 + sub0) ^ (kg << 4));
            const int e1 = (((kg << 10) + (a_m + 64) * 8 + sub0) ^ (kg << 4));
            s16x4 h0, l0, h1, l1;
            #pragma unroll
            for (int j = 0; j < 4; ++j) {
                short h = f2bf(v0[j]); h0[j] = h; l0[j] = f2bf(v0[j] - bf2f(h));
                short g = f2bf(v1[j]); h1[j] = g; l1[j] = f2bf(v1[j] - bf2f(g));
            }
            *(s16x4*)(&As_hi[e0]) = h0; *(s16x4*)(&As_lo[e0]) = l0;
            *(s16x4*)(&As_hi[e1]) = h1; *(s16x4*)(&As_lo[e1]) = l1;
        }
        // ---- stage B (4 k-rows x 2 n) ----
        {
            const float* bp = B + (size_t)(k0 + b_kq * 4) * N + n0 + b_np * 2;
            f32x2 u0 = *(const f32x2*)bp;
            f32x2 u1 = *(const f32x2*)(bp + (size_t)N);
            f32x2 u2 = *(const f32x2*)(bp + (size_t)2 * N);
            f32x2 u3 = *(const f32x2*)(bp + (size_t)3 * N);
            const int kg = b_kq >> 1, sub0 = (b_kq & 1) * 4;
            #pragma unroll
            for (int e = 0; e < 2; ++e) {
                float vals[4] = {u0[e], u1[e], u2[e], u3[e]};
                s16x4 h, l;
                #pragma unroll
                for (int j = 0; j < 4; ++j) {
                    short hh = f2bf(vals[j]); h[j] = hh; l[j] = f2bf(vals[j] - bf2f(hh));
                }
                const int ei = (((kg << 10) + (b_np * 2 + e) * 8 + sub0) ^ (kg << 4));
                *(s16x4*)(&Bs_hi[ei]) = h; *(s16x4*)(&Bs_lo[ei]) = l;
            }
        }
        __syncthreads();
        // ---- compute: 2 m-frags x 4 n-frags x 3 split-MFMAs ----
        s16x8 a_hi[2], a_lo[2];
        #pragma unroll
        for (int i = 0; i < 2; ++i) {
            const int m = wm * 32 + i * 16 + lr;
            const int e = (((lg << 10) + m * 8) ^ (lg << 4));
            a_hi[i] = *(const s16x8*)(&As_hi[e]);
            a_lo[i] = *(const s16x8*)(&As_lo[e]);
        }
        #pragma unroll
        for (int j = 0; j < 4; ++j) {
            const int n = wn * 64 + j * 16 + lr;
            const int e = (((lg << 10) + n * 8) ^ (lg << 4));
            v8bf b_hi = as_bf(*(const s16x8*)(&Bs_hi[e]));
            v8bf b_lo = as_bf(*(const s16x8*)(&Bs_lo[e]));
            #pragma unroll
            for (int i = 0; i < 2; ++i) {
                v8bf ah = as_bf(a_hi[i]), al = as_bf(a_lo[i]);
                acc[i][j] = __builtin_amdgcn_mfma_f32_16x16x32_bf16(ah, b_hi, acc[i][j], 0, 0, 0);
                acc[i][j] = __builtin_amdgcn_mfma_f32_16x16x32_bf16(ah, b_lo, acc[i][j], 0, 0, 0);
                acc[i][j] = __builtin_amdgcn_mfma_f32_16x16x32_bf16(al, b_hi, acc[i][j], 0, 0, 0);
            }
        }
        __syncthreads();
    }
    // ---- epilogue: partial tile -> P[ks] ----
    float* pb = P + (size_t)blockIdx.z * 512 * N;
    #pragma unroll
    for (int i = 0; i < 2; ++i)
        #pragma unroll
        for (int j = 0; j < 4; ++j) {
            const int gn = n0 + wn * 64 + j * 16 + lr;
            #pragma unroll
            for (int rr = 0; rr < 4; ++rr) {
                const int gm = m0 + wm * 32 + i * 16 + lg * 4 + rr;
                pb[(size_t)gm * N + gn] = acc[i][j][rr];
            }
        }
}

// ---------------- kernel 3: 4-way partial reduce + bias + relu ----------------
__global__ __launch_bounds__(256) void reduce_bias_relu(
    const float* __restrict__ P, const float* __restrict__ bias,
    float* __restrict__ out, int total, int N, int do_relu) {
    int i = (blockIdx.x * 256 + threadIdx.x) * 4;
    if (i >= total) return;
    f32x4 a0 = *(const f32x4*)(P + i);
    f32x4 a1 = *(const f32x4*)(P + (size_t)total + i);
    f32x4 a2 = *(const f32x4*)(P + (size_t)2 * total + i);
    f32x4 a3 = *(const f32x4*)(P + (size_t)3 * total + i);
    f32x4 bb = *(const f32x4*)(bias + (i % N));
    f32x4 r = (a0 + a1) + (a2 + a3) + bb;
    if (do_relu) {
        #pragma unroll
        for (int j = 0; j < 4; ++j) r[j] = fmaxf(r[j], 0.f);
    }
    *(f32x4*)(out + i) = r;
}

// ---------------- kernel 4: heads (loc + score) ----------------
__global__ __launch_bounds__(128) void heads_kernel(
    const float* __restrict__ fc7,
    const float* __restrict__ w_loc, const float* __restrict__ b_loc,
    const float* __restrict__ w_score, const float* __restrict__ b_score,
    float* __restrict__ out, int nroi) {
    __shared__ float row[4096];
    const int r = blockIdx.x;
    const float* fr = fc7 + (size_t)r * 4096;
    for (int i = threadIdx.x; i < 4096; i += 128) row[i] = fr[i];
    __syncthreads();
    const int n = threadIdx.x;
    if (n < 84) {
        float s0 = 0.f, s1 = 0.f, s2 = 0.f, s3 = 0.f;
        for (int k = 0; k < 4096; k += 4) {
            s0 += row[k+0] * w_loc[(size_t)(k+0) * 84 + n];
            s1 += row[k+1] * w_loc[(size_t)(k+1) * 84 + n];
            s2 += row[k+2] * w_loc[(size_t)(k+2) * 84 + n];
            s3 += row[k+3] * w_loc[(size_t)(k+3) * 84 + n];
        }
        out[(size_t)r * 84 + n] = b_loc[n] + ((s0 + s1) + (s2 + s3));
    } else if (n < 105) {
        const int c = n - 84;
        float s0 = 0.f, s1 = 0.f, s2 = 0.f, s3 = 0.f;
        for (int k = 0; k < 4096; k += 4) {
            s0 += row[k+0] * w_score[(size_t)(k+0) * 21 + c];
            s1 += row[k+1] * w_score[(size_t)(k+1) * 21 + c];
            s2 += row[k+2] * w_score[(size_t)(k+2) * 21 + c];
            s3 += row[k+3] * w_score[(size_t)(k+3) * 21 + c];
        }
        out[(size_t)nroi * 84 + (size_t)r * 21 + c] = b_score[c] + ((s0 + s1) + (s2 + s3));
    }
}

// ---------------- launch ----------------
extern "C" void kernel_launch(void* const* d_in, const int* in_sizes, int n_in,
                              void* d_out, int out_size, void* d_ws, size_t ws_size,
                              hipStream_t stream) {
    const float* feat2   = (const float*)d_in[0];
    const float* feat3   = (const float*)d_in[1];
    const float* feat4   = (const float*)d_in[2];
    const float* rois    = (const float*)d_in[3];
    const int*   roi_idx = (const int*)d_in[4];
    const float* w_fc1   = (const float*)d_in[5];
    const float* b_fc1   = (const float*)d_in[6];
    const float* w_fc2   = (const float*)d_in[7];
    const float* b_fc2   = (const float*)d_in[8];
    const float* w_loc   = (const float*)d_in[9];
    const float* b_loc   = (const float*)d_in[10];
    const float* w_score = (const float*)d_in[11];
    const float* b_score = (const float*)d_in[12];
    float* out = (float*)d_out;

    const int nroi = in_sizes[4];            // 512
    const int FDIM = 25088;                  // 512*7*7
    const int HID  = 4096;

    // ws layout (bytes):
    //   flat  : nroi*25088*4           = 51,380,224   (also reused as fc7 after FC1)
    //   part  : 4 * 512*4096*4         = 33,554,432
    //   fc6   : 512*4096*4             =  8,388,608
    char* ws = (char*)d_ws;
    const size_t off_flat = 0;
    const size_t off_part = 51380224;
    const size_t off_fc6  = off_part + 33554432;
    const size_t need     = off_fc6 + 8388608;
    if (ws_size < need) return;  // visible failure -> repack scratch next round
    float* flat = (float*)(ws + off_flat);
    float* part = (float*)(ws + off_part);
    float* fc6  = (float*)(ws + off_fc6);
    float* fc7  = (float*)(ws + off_flat);   // reuse flat region after FC1

    // 1) RoI-align with per-roi level select
    roi_pool_kernel<<<nroi, 256, 0, stream>>>(feat2, feat3, feat4, rois, roi_idx, flat);

    // 2) FC1: [512,25088] x [25088,4096]  (KSPLIT=4 -> ksub=6272)
    gemm_split_kernel<<<dim3(HID/128, 512/128, GKS), 512, 0, stream>>>(
        flat, w_fc1, part, FDIM, HID, FDIM / GKS);
    reduce_bias_relu<<<(512 * HID / 4 + 255) / 256, 256, 0, stream>>>(
        part, b_fc1, fc6, 512 * HID, HID, 1);

    // 3) FC2: [512,4096] x [4096,4096]  (ksub=1024)
    gemm_split_kernel<<<dim3(HID/128, 512/128, GKS), 512, 0, stream>>>(
        fc6, w_fc2, part, HID, HID, HID / GKS);
    reduce_bias_relu<<<(512 * HID / 4 + 255) / 256, 256, 0, stream>>>(
        part, b_fc2, fc7, 512 * HID, HID, 1);

    // 4) heads
    heads_kernel<<<nroi, 128, 0, stream>>>(fc7, w_loc, b_loc, w_score, b_score, out, nroi);
}

// Round 2
// 1270.861 us; speedup vs baseline: 1.1079x; 1.1079x over previous
//
#include <hip/hip_runtime.h>
#include <hip/hip_bf16.h>

typedef __attribute__((ext_vector_type(4))) float  f32x4;
typedef __attribute__((ext_vector_type(8))) short  s16x8;
typedef __attribute__((ext_vector_type(8))) __bf16 v8bf;

__device__ __forceinline__ unsigned short f2bf_u(float f) {
    unsigned u = __builtin_bit_cast(unsigned, f);
    unsigned r = (u + 0x7fffu + ((u >> 16) & 1u)) >> 16;   // RNE
    return (unsigned short)r;
}
__device__ __forceinline__ float bfu2f(unsigned short s) {
    unsigned u = ((unsigned)s) << 16;
    return __builtin_bit_cast(float, u);
}

// =========================================================================
// Kernel 1: level-select + RoI-align, writing A directly as split-bf16 in
// fragment-major tiled layout: elem(mb,kb,ko,row,j) = (((mb*KB+kb)*4+ko)*16+row)*8+j
// (KB = 25088/32 = 784; mb = roi/16, row = roi%16)
// grid (512 rois, 7), 448 threads. Each block covers k-range [by*3584, +3584).
// =========================================================================
__global__ __launch_bounds__(448) void roi_pool_split(
    const float* __restrict__ feat2, const float* __restrict__ feat3,
    const float* __restrict__ feat4, const float* __restrict__ rois,
    const int* __restrict__ roi_idx,
    unsigned short* __restrict__ Ah, unsigned short* __restrict__ Al) {
    const int r  = blockIdx.x;
    const int by = blockIdx.y;
    const int t  = threadIdx.x;

    __shared__ int   syA[14], syB[14], sxA[14], sxB[14];
    __shared__ float sly[14], slx[14];
    __shared__ float pool[3584];

    // per-roi level select (uniform per block; every thread computes it)
    const float y1r = rois[r*4+0], x1r = rois[r*4+1];
    const float y2r = rois[r*4+2], x2r = rois[r*4+3];
    float lvlf = rintf(log2f(sqrtf((y2r - y1r + 1.0f) * (x2r - x1r + 1.0f)) / 224.0f) + 4.0f);
    lvlf = fminf(fmaxf(lvlf, 2.0f), 4.0f);
    const int lvl = (int)lvlf;
    const float* feat; int H; float scale;
    if (lvl == 2)      { feat = feat2; H = 200; scale = 0.25f;   }
    else if (lvl == 3) { feat = feat3; H = 100; scale = 0.125f;  }
    else               { feat = feat4; H = 50;  scale = 0.0625f; }
    const int W = H;
    const int HW = H * W;

    const float x1 = x1r*scale, y1 = y1r*scale, x2 = x2r*scale, y2 = y2r*scale;
    const float roiw = fmaxf(x2 - x1, 1.0f), roih = fmaxf(y2 - y1, 1.0f);

    if (t < 14) {
        float off = ((float)t + 0.5f) * (1.0f/14.0f);
        float ys = fminf(fmaxf(y1 + roih*off, 0.0f), (float)(H-1));
        float yf = floorf(ys);
        int ya = (int)yf;
        syA[t] = ya * W; sly[t] = ys - yf; syB[t] = min(ya + 1, H-1) * W;
    } else if (t < 28) {
        int j = t - 14;
        float off = ((float)j + 0.5f) * (1.0f/14.0f);
        float xs = fminf(fmaxf(x1 + roiw*off, 0.0f), (float)(W-1));
        float xf = floorf(xs);
        int xa = (int)xf;
        sxA[j] = xa; slx[j] = xs - xf; sxB[j] = min(xa + 1, W-1);
    }
    __syncthreads();

    const float* fb = feat + (size_t)roi_idx[r] * 512 * HW;
    const int wv = t >> 6, lane = t & 63;

    // gather phase: at fixed j, a wave's 64 lanes read 64 CONSECUTIVE k (locality)
    #pragma unroll
    for (int j = 0; j < 8; ++j) {
        const int kl = wv*512 + j*64 + lane;       // local k in [0,3584)
        const int kg = by*3584 + kl;               // global k in [0,25088)
        const int c  = kg / 49;
        const int p  = kg - c*49;
        const int oy = p / 7;
        const int ox = p - oy*7;
        const float* fc = fb + (size_t)c * HW;
        float acc = 0.0f;
        #pragma unroll
        for (int sy = 0; sy < 2; ++sy) {
            const int iy = oy*2 + sy;
            const int ra = syA[iy], rb = syB[iy];
            const float ly = sly[iy], wy0 = 1.0f - ly;
            #pragma unroll
            for (int sx = 0; sx < 2; ++sx) {
                const int ix = ox*2 + sx;
                const int xa = sxA[ix], xb = sxB[ix];
                const float lx = slx[ix], wx0 = 1.0f - lx;
                acc += fc[ra+xa]*wy0*wx0 + fc[ra+xb]*wy0*lx
                     + fc[rb+xa]*ly*wx0  + fc[rb+xb]*ly*lx;
            }
        }
        pool[kl] = acc * 0.25f;
    }
    __syncthreads();

    // pack phase: each thread -> 8 consecutive k -> one 16B hi + 16B lo chunk
    const int k0l = t * 8;
    const int k0  = by*3584 + k0l;
    f32x4 v0 = *(const f32x4*)(&pool[k0l]);
    f32x4 v1 = *(const f32x4*)(&pool[k0l+4]);
    float v[8] = {v0[0],v0[1],v0[2],v0[3],v1[0],v1[1],v1[2],v1[3]};
    s16x8 hi, lo;
    #pragma unroll
    for (int i = 0; i < 8; ++i) {
        unsigned short h = f2bf_u(v[i]);
        hi[i] = (short)h;
        lo[i] = (short)f2bf_u(v[i] - bfu2f(h));
    }
    const int mb = r >> 4, row = r & 15;
    const int kb = k0 >> 5, ko = (k0 >> 3) & 3;
    const size_t off = ((((size_t)mb*784 + kb)*4 + ko)*16 + row)*8;
    *(s16x8*)(Ah + off) = hi;
    *(s16x8*)(Al + off) = lo;
}

// =========================================================================
// Kernel 2: zero P
// =========================================================================
__global__ __launch_bounds__(256) void zero_f32(float* __restrict__ p, int n4) {
    int i = blockIdx.x*256 + threadIdx.x;
    if (i < n4) ((f32x4*)p)[i] = f32x4{0.f,0.f,0.f,0.f};
}

// =========================================================================
// Kernel 3: split-bf16 3-term MFMA GEMM.
// C = A*B, A[512][K] given as tiled split-bf16 planes (Ah,Al), B[K][4096] fp32
// (converted in-kernel, outside the MFMA critical path), result atomically
// accumulated into P[512][4096] (P pre-zeroed; grid.z folded into blockIdx.x).
// Tile 256x256xBK32, 512 thr (8 waves as 2m x 4n, wave-tile 128x64),
// LDS 2 x 64KB buffers: [Ah 16K][Al 16K][Bh 16K][Bl 16K].
// Block swizzle: zblk == XCD id (each XCD streams one K-slice).
// =========================================================================
__global__ __launch_bounds__(512, 2) void gemm_split3(
    const unsigned short* __restrict__ Ah, const unsigned short* __restrict__ Al,
    const float* __restrict__ B, float* __restrict__ P,
    const int K, const int ksub) {
    extern __shared__ char lds[];          // 131072 bytes
    const int tid  = threadIdx.x;
    const int lane = tid & 63;
    const int wv   = tid >> 6;
    const int wm   = wv >> 2;              // 0..1 -> rows wm*128
    const int wn   = wv & 3;               // 0..3 -> cols wn*64

    int L = (int)blockIdx.x;
    L = (L & 7) * 32 + (L >> 3);           // phys->logical: 32 consecutive L per XCD
    const int mblk = L & 1;
    const int nblk = (L >> 1) & 15;
    const int zblk = L >> 5;               // == XCD id
    const int m0 = mblk * 256;
    const int n0 = nblk * 256;
    const int KB = K >> 5;
    const int kb0 = (zblk * ksub) >> 5;
    const int nsteps = ksub >> 5;

    // B staging mapping: thread -> (col 0..15, nb 0..15, kq 0..1)
    const int b_col = tid & 15;
    const int b_nb  = (tid >> 4) & 15;
    const int b_kq  = tid >> 8;
    const float* Bbase = B + (size_t)(n0 + b_nb*16 + b_col);

    f32x4 acc[8][4];
    #pragma unroll
    for (int i = 0; i < 8; ++i)
        #pragma unroll
        for (int j = 0; j < 4; ++j) acc[i][j] = f32x4{0.f,0.f,0.f,0.f};

    float bv[16];

    auto loadB = [&](int kb) {
        const float* bp = Bbase + (size_t)(kb*32 + b_kq*16) * 4096;
        #pragma unroll
        for (int i = 0; i < 16; ++i) bv[i] = bp[(size_t)i * 4096];
    };
    // A: 32 chunks (plane=c>>4, mbi=c&15), wave wv stages chunks wv*4..wv*4+3.
    // Tiled global layout == LDS layout: 1KB contiguous per chunk, lane-linear.
    auto stageA = [&](int kb, char* buf) {
        #pragma unroll
        for (int c = 0; c < 4; ++c) {
            const int ch = wv*4 + c;
            const unsigned short* src = ((ch & 16) ? Al : Ah)
                + ((size_t)((m0 >> 4) + (ch & 15)) * KB + kb) * 512 + lane*8;
            char* dst = buf + (ch >> 4) * 16384 + (ch & 15) * 1024;
            __builtin_amdgcn_global_load_lds((const void*)src, (void*)dst, 16, 0, 0);
        }
    };
    auto convB = [&](char* buf) {
        #pragma unroll
        for (int o2 = 0; o2 < 2; ++o2) {
            s16x8 hi, lo;
            #pragma unroll
            for (int i = 0; i < 8; ++i) {
                float f = bv[o2*8 + i];
                unsigned short h = f2bf_u(f);
                hi[i] = (short)h;
                lo[i] = (short)f2bf_u(f - bfu2f(h));
            }
            const int oct = b_kq*2 + o2;
            char* p = buf + 32768 + b_nb*1024 + oct*256 + b_col*16;
            *(s16x8*)p = hi;
            *(s16x8*)(p + 16384) = lo;
        }
    };
    auto mfma_half = [&](int h, const char* buf) {
        s16x8 ah[4], al[4];
        #pragma unroll
        for (int mf = 0; mf < 4; ++mf) {
            const int ch = wm*8 + h*4 + mf;
            ah[mf] = *(const s16x8*)(buf + ch*1024 + lane*16);
            al[mf] = *(const s16x8*)(buf + 16384 + ch*1024 + lane*16);
        }
        #pragma unroll
        for (int nf = 0; nf < 4; ++nf) {
            const int nb = wn*4 + nf;
            v8bf bh = __builtin_bit_cast(v8bf, *(const s16x8*)(buf + 32768 + nb*1024 + lane*16));
            v8bf bl = __builtin_bit_cast(v8bf, *(const s16x8*)(buf + 49152 + nb*1024 + lane*16));
            #pragma unroll
            for (int mf = 0; mf < 4; ++mf) {
                v8bf a1 = __builtin_bit_cast(v8bf, ah[mf]);
                v8bf a2 = __builtin_bit_cast(v8bf, al[mf]);
                const int mi = h*4 + mf;
                acc[mi][nf] = __builtin_amdgcn_mfma_f32_16x16x32_bf16(a1, bh, acc[mi][nf], 0,0,0);
                acc[mi][nf] = __builtin_amdgcn_mfma_f32_16x16x32_bf16(a1, bl, acc[mi][nf], 0,0,0);
                acc[mi][nf] = __builtin_amdgcn_mfma_f32_16x16x32_bf16(a2, bh, acc[mi][nf], 0,0,0);
            }
        }
    };

    char* buf0 = lds;
    char* buf1 = lds + 65536;

    // prologue: stage step 0 into buf0
    stageA(kb0, buf0);
    loadB(kb0);
    convB(buf0);
    __syncthreads();

    for (int s = 0; s < nsteps; ++s) {
        char* cur = (s & 1) ? buf1 : buf0;
        char* nxt = (s & 1) ? buf0 : buf1;
        const bool more = (s + 1 < nsteps);
        if (more) { stageA(kb0 + s + 1, nxt); loadB(kb0 + s + 1); }
        mfma_half(0, cur);
        if (more) convB(nxt);      // overlaps with matrix pipe; loads done by now
        mfma_half(1, cur);
        __syncthreads();           // drains A glds + orders buffer swap
    }

    // epilogue: atomic accumulate (k-split partial)
    const int orow = (lane >> 4) * 4;
    const int ocol = lane & 15;
    #pragma unroll
    for (int mi = 0; mi < 8; ++mi) {
        const int gm = m0 + wm*128 + mi*16 + orow;
        #pragma unroll
        for (int nf = 0; nf < 4; ++nf) {
            const int gn = n0 + wn*64 + nf*16 + ocol;
            float* pp = P + (size_t)gm*4096 + gn;
            #pragma unroll
            for (int rr = 0; rr < 4; ++rr)
                atomicAdd(pp + (size_t)rr*4096, acc[mi][nf][rr]);
        }
    }
}

// =========================================================================
// Kernel 4: P -> bias+relu -> split-bf16 tiled A planes (for next GEMM)
// (KB = 4096/32 = 128). 262144 threads, 8 elems each.
// =========================================================================
__global__ __launch_bounds__(256) void reduce_split(
    const float* __restrict__ P, const float* __restrict__ bias,
    unsigned short* __restrict__ Ah, unsigned short* __restrict__ Al) {
    const int g = blockIdx.x*256 + threadIdx.x;
    const int m = g >> 9;
    const int k0 = (g & 511) * 8;
    const float* pp = P + (size_t)m*4096 + k0;
    f32x4 v0 = *(const f32x4*)pp, v1 = *(const f32x4*)(pp + 4);
    f32x4 b0 = *(const f32x4*)(bias + k0), b1 = *(const f32x4*)(bias + k0 + 4);
    float v[8];
    #pragma unroll
    for (int i = 0; i < 4; ++i) { v[i] = fmaxf(v0[i] + b0[i], 0.f); v[i+4] = fmaxf(v1[i] + b1[i], 0.f); }
    s16x8 hi, lo;
    #pragma unroll
    for (int i = 0; i < 8; ++i) {
        unsigned short h = f2bf_u(v[i]);
        hi[i] = (short)h;
        lo[i] = (short)f2bf_u(v[i] - bfu2f(h));
    }
    const int mb = m >> 4, row = m & 15;
    const int kb = k0 >> 5, ko = (k0 >> 3) & 3;
    const size_t off = ((((size_t)mb*128 + kb)*4 + ko)*16 + row)*8;
    *(s16x8*)(Ah + off) = hi;
    *(s16x8*)(Al + off) = lo;
}

// =========================================================================
// Kernel 5: P -> bias+relu -> fc7 fp32 (row-major, for heads)
// =========================================================================
__global__ __launch_bounds__(256) void reduce_bias_relu_f32(
    const float* __restrict__ P, const float* __restrict__ bias,
    float* __restrict__ out) {
    const int g = blockIdx.x*256 + threadIdx.x;
    const int m = g >> 9;
    const int k0 = (g & 511) * 8;
    const float* pp = P + (size_t)m*4096 + k0;
    f32x4 v0 = *(const f32x4*)pp, v1 = *(const f32x4*)(pp + 4);
    f32x4 b0 = *(const f32x4*)(bias + k0), b1 = *(const f32x4*)(bias + k0 + 4);
    #pragma unroll
    for (int i = 0; i < 4; ++i) { v0[i] = fmaxf(v0[i] + b0[i], 0.f); v1[i] = fmaxf(v1[i] + b1[i], 0.f); }
    float* op = out + (size_t)m*4096 + k0;
    *(f32x4*)op = v0;
    *(f32x4*)(op + 4) = v1;
}

// =========================================================================
// Kernel 6: heads. 1 block per roi; 105 cols x 2 k-halves = 210 active threads.
// =========================================================================
__global__ __launch_bounds__(256) void heads_kernel(
    const float* __restrict__ fc7,
    const float* __restrict__ w_loc, const float* __restrict__ b_loc,
    const float* __restrict__ w_score, const float* __restrict__ b_score,
    float* __restrict__ out, int nroi) {
    __shared__ float row[4096];
    __shared__ float part[105];
    const int r = blockIdx.x, t = threadIdx.x;
    const float* fr = fc7 + (size_t)r * 4096;
    for (int i = t; i < 4096; i += 256) row[i] = fr[i];
    __syncthreads();
    const bool active = t < 210;
    int half = 0, c = 0;
    float s = 0.f;
    if (active) {
        half = t / 105; c = t - half*105;
        const float* wp; int ldw;
        if (c < 84) { wp = w_loc + c; ldw = 84; }
        else        { wp = w_score + (c - 84); ldw = 21; }
        const int kb = half * 2048;
        #pragma unroll 8
        for (int k = 0; k < 2048; ++k)
            s += row[kb + k] * wp[(size_t)(kb + k) * ldw];
    }
    if (active && half) part[c] = s;
    __syncthreads();
    if (active && !half) {
        float o = s + part[c];
        if (c < 84) out[(size_t)r*84 + c] = o + b_loc[c];
        else        out[(size_t)nroi*84 + (size_t)r*21 + (c - 84)] = o + b_score[c - 84];
    }
}

// =========================================================================
// launch
// =========================================================================
extern "C" void kernel_launch(void* const* d_in, const int* in_sizes, int n_in,
                              void* d_out, int out_size, void* d_ws, size_t ws_size,
                              hipStream_t stream) {
    const float* feat2   = (const float*)d_in[0];
    const float* feat3   = (const float*)d_in[1];
    const float* feat4   = (const float*)d_in[2];
    const float* rois    = (const float*)d_in[3];
    const int*   roi_idx = (const int*)d_in[4];
    const float* w_fc1   = (const float*)d_in[5];
    const float* b_fc1   = (const float*)d_in[6];
    const float* w_fc2   = (const float*)d_in[7];
    const float* b_fc2   = (const float*)d_in[8];
    const float* w_loc   = (const float*)d_in[9];
    const float* b_loc   = (const float*)d_in[10];
    const float* w_score = (const float*)d_in[11];
    const float* b_score = (const float*)d_in[12];
    float* out = (float*)d_out;
    const int nroi = in_sizes[4];   // 512

    // ws layout (bytes)
    char* ws = (char*)d_ws;
    const size_t off_A1h = 0;                          // 512*25088*2 = 25,690,112
    const size_t off_A1l = 25690112;
    const size_t off_P   = 51380224;                   // 512*4096*4  =  8,388,608
    const size_t off_A2h = 59768832;                   // 512*4096*2  =  4,194,304
    const size_t off_A2l = 63963136;
    const size_t off_f7  = 68157440;                   // 512*4096*4
    const size_t need    = 76546048;
    if (ws_size < need) return;
    unsigned short* A1h = (unsigned short*)(ws + off_A1h);
    unsigned short* A1l = (unsigned short*)(ws + off_A1l);
    float*          P   = (float*)(ws + off_P);
    unsigned short* A2h = (unsigned short*)(ws + off_A2h);
    unsigned short* A2l = (unsigned short*)(ws + off_A2l);
    float*          fc7 = (float*)(ws + off_f7);

    hipFuncSetAttribute((const void*)gemm_split3,
                        hipFuncAttributeMaxDynamicSharedMemorySize, 131072);

    // 1) RoI-align -> tiled split A1
    roi_pool_split<<<dim3(512, 7), 448, 0, stream>>>(feat2, feat3, feat4, rois, roi_idx, A1h, A1l);

    // 2) FC1: [512,25088] x [25088,4096], k-split 8 via atomics into zeroed P
    zero_f32<<<2048, 256, 0, stream>>>(P, 524288);
    gemm_split3<<<256, 512, 131072, stream>>>(A1h, A1l, w_fc1, P, 25088, 3136);
    reduce_split<<<1024, 256, 0, stream>>>(P, b_fc1, A2h, A2l);

    // 3) FC2: [512,4096] x [4096,4096]
    zero_f32<<<2048, 256, 0, stream>>>(P, 524288);
    gemm_split3<<<256, 512, 131072, stream>>>(A2h, A2l, w_fc2, P, 4096, 512);
    reduce_bias_relu_f32<<<1024, 256, 0, stream>>>(P, b_fc2, fc7);

    // 4) heads
    heads_kernel<<<512, 256, 0, stream>>>(fc7, w_loc, b_loc, w_score, b_score, out, nroi);
}